// Round 17
// baseline (220.225 us; speedup 1.0000x reference)
//
#include <hip/hip_runtime.h>
#include <hip/hip_bf16.h>

#define DEVI __device__ __forceinline__

typedef __attribute__((ext_vector_type(4))) float f32x4;
typedef __attribute__((ext_vector_type(16))) float f32x16;
typedef __attribute__((ext_vector_type(8))) short s16x8;
typedef __attribute__((ext_vector_type(4))) short s16x4;
typedef __attribute__((ext_vector_type(2))) unsigned u32x2;

DEVI ushort f2bf(float f) {
  union { float f; unsigned u; } v; v.f = f;
  unsigned r = v.u + 0x7FFFu + ((v.u >> 16) & 1u);
  return (ushort)(r >> 16);
}

DEVI void gload_lds16(const void* g, void* l) {
  __builtin_amdgcn_global_load_lds((const __attribute__((address_space(1))) void*)g,
                                   (__attribute__((address_space(3))) void*)l, 16, 0, 0);
}

#define MFMA16 __builtin_amdgcn_mfma_f32_16x16x32_bf16
#define SBAR() __builtin_amdgcn_s_barrier()
#define LGKM0() asm volatile("s_waitcnt lgkmcnt(0)")

// Cross-half (lane i <-> lane i+32) max via the permlane32_swap BUILTIN
// (round-10 lesson: inline-asm "+v","+v" self-swap corrupted the row max).
DEVI float plswap_max(float x) {
  union { float f; unsigned u; } a; a.f = x;
  u32x2 r = __builtin_amdgcn_permlane32_swap(a.u, a.u, false, false);
  union { unsigned u; float f; } o0, o1; o0.u = r[0]; o1.u = r[1];
  return fmaxf(o0.f, o1.f);
}

// ---- BK=64 staging/frag (rows of 64 bf16 = 8 chunks), swizzle c ^ (row&7) ----
DEVI void stage128q(const ushort* __restrict__ gsrc, int K, ushort* ld, int tid) {
  #pragma unroll
  for (int j = 0; j < 4; ++j) {
    const int ci = j * 256 + tid;
    const int row = ci >> 3, c = ci & 7;
    gload_lds16(gsrc + (size_t)row * K + ((c ^ (row & 7)) << 3),
                ld + (size_t)(j * 256 + (tid & ~63)) * 8);
  }
}
DEVI s16x8 ldfrag(const ushort* tile, int row, int kc) {
  return *(const s16x8*)((const char*)tile + row * 128 + ((kc ^ (row & 7)) << 4));
}

// =====================================================================
// Single-barrier triple-B K-loop, BK=64, BM=BN=128 (champion engine).
// =====================================================================
DEVI void kloop3(const ushort* __restrict__ A, const ushort* __restrict__ BT,
                 ushort* Asm, ushort* Bsm, int m0, int n0, int K, int NKT,
                 f32x4 (&acc)[4][4], int tid, int wm, int wn, int g, int l15) {
  stage128q(A + (size_t)m0 * K, K, Asm, tid);
  stage128q(BT + (size_t)n0 * K, K, Bsm, tid);
  stage128q(BT + (size_t)n0 * K + 64, K, Bsm + 8192, tid);
  asm volatile("s_waitcnt vmcnt(4)");
  SBAR();

  int rd = 0;
  #pragma unroll 1
  for (int t = 0; t < NKT; ++t) {
    const ushort* Ah = Asm + (t & 1) * 8192;
    const ushort* Bh = Bsm + rd * 8192;
    s16x8 af[4][2], bfr[4][2];

    #pragma unroll
    for (int ks = 0; ks < 2; ++ks) {
      #pragma unroll
      for (int ni = 0; ni < 4; ++ni)
        bfr[ni][ks] = ldfrag(Bh, wn * 64 + ni * 16 + l15, ks * 4 + g);
      #pragma unroll
      for (int mi = 0; mi < 4; ++mi)
        af[mi][ks] = ldfrag(Ah, wm * 64 + mi * 16 + l15, ks * 4 + g);
    }
    if (t + 1 < NKT)
      stage128q(A + (size_t)m0 * K + (t + 1) * 64, K, Asm + ((t + 1) & 1) * 8192, tid);
    int wr = rd + 2; if (wr >= 3) wr -= 3;
    if (t + 2 < NKT)
      stage128q(BT + (size_t)n0 * K + (t + 2) * 64, K, Bsm + wr * 8192, tid);

    LGKM0();
    __builtin_amdgcn_sched_barrier(0);
    __builtin_amdgcn_s_setprio(1);
    #pragma unroll
    for (int mi = 0; mi < 4; ++mi)
      #pragma unroll
      for (int ni = 0; ni < 2; ++ni)
        #pragma unroll
        for (int ks = 0; ks < 2; ++ks)
          acc[mi][ni] = MFMA16(af[mi][ks], bfr[ni][ks], acc[mi][ni], 0, 0, 0);
    #pragma unroll
    for (int mi = 0; mi < 4; ++mi)
      #pragma unroll
      for (int ni = 0; ni < 2; ++ni)
        #pragma unroll
        for (int ks = 0; ks < 2; ++ks)
          acc[mi][2 + ni] = MFMA16(af[mi][ks], bfr[2 + ni][ks], acc[mi][2 + ni], 0, 0, 0);
    __builtin_amdgcn_s_setprio(0);

    if (t + 2 < NKT)      asm volatile("s_waitcnt vmcnt(4)");
    else if (t + 1 < NKT) asm volatile("s_waitcnt vmcnt(0)");
    SBAR();
    rd = (rd == 2) ? 0 : rd + 1;
  }
}

// =====================================================================
// Fused preamble (round-15 win).
// =====================================================================
__global__ __launch_bounds__(256) void preamble_k(const float* __restrict__ x,
                                                  const float* __restrict__ Wq,
                                                  const float* __restrict__ Wkv,
                                                  const float* __restrict__ Wo,
                                                  ushort* __restrict__ xb,
                                                  ushort* __restrict__ WqkvT,
                                                  ushort* __restrict__ WoT,
                                                  float2* __restrict__ tab) {
  const int id = blockIdx.x;
  const int tid = threadIdx.x;

  if (id >= 2560) {
    if (id < 10752) {                       // ---- elementwise cast ----
      const int lid = id - 2560;
      int i = (lid * 256 + tid) * 4;
      float4 v = *(const float4*)(x + i);
      ushort4 o;
      o.x = f2bf(v.x); o.y = f2bf(v.y); o.z = f2bf(v.z); o.w = f2bf(v.w);
      *(ushort4*)(xb + i) = o;
    } else {                                // ---- rope tables ----
      const int lid = id - 10752;
      int idx = lid * 256 + tid;            // T*32 = 65536
      int t = idx >> 5, i = idx & 31;
      float inv = expf(-(float)i * 0.28782313662425575f);  // ln(10000)/32
      float ang = (float)t * inv;
      tab[idx] = make_float2(cosf(ang), sinf(ang));
    }
    return;
  }

  // ---- transpose+cast branch ----
  __shared__ ushort tile[64][66];
  const float* in; ushort* out; int R, C, bx, by;
  if (id < 1024)        { in = Wq;  out = WqkvT;              R = 2048; C = 2048; bx = id & 31;          by = id >> 5; }
  else if (id < 1536)   { in = Wkv; out = WqkvT + 2048*2048;  R = 2048; C = 1024; bx = (id-1024) & 15;   by = (id-1024) >> 4; }
  else                  { in = Wo;  out = WoT;                R = 2048; C = 2048; bx = (id-1536) & 31;   by = (id-1536) >> 5; }
  const int r0 = by * 64, c0 = bx * 64;
  #pragma unroll
  for (int j = 0; j < 16; ++j) {
    int idx = j * 256 + tid;
    int r = idx >> 6, c = idx & 63;
    tile[c][r] = f2bf(in[(size_t)(r0 + r) * C + c0 + c]);
  }
  __syncthreads();
  #pragma unroll
  for (int j = 0; j < 16; ++j) {
    int idx = j * 256 + tid;
    int c = idx >> 6, r = idx & 63;
    out[(size_t)(c0 + c) * R + r0 + r] = tile[c][r];
  }
}

// ---------------- fused QKV GEMM: 128x128 tile, single-barrier engine (r11) ----------------
__global__ __launch_bounds__(256) void gemm_qkv_3b(const ushort* __restrict__ A,
                                                   const ushort* __restrict__ BT,
                                                   const float2* __restrict__ tab,
                                                   ushort* __restrict__ Qp,
                                                   ushort* __restrict__ Kp,
                                                   ushort* __restrict__ Vp) {
  constexpr int K = 2048, NKT = 32;
  __shared__ __attribute__((aligned(128))) ushort smem[40960];   // 80 KiB
  ushort* Asm = smem;            // [2][128*64]
  ushort* Bsm = smem + 16384;    // [3][128*64]
  ushort* Ot = smem;             // epilogue tile [128][132]

  const int tid = threadIdx.x;
  const int ln = tid & 63, wv = tid >> 6;
  const int g = ln >> 4, l15 = ln & 15, l31 = ln & 31, hi = ln >> 5;
  const int wm = wv >> 1, wn = wv & 1;
  const int m0 = blockIdx.y * 128, n0 = blockIdx.x * 128;

  f32x4 acc[4][4];
  #pragma unroll
  for (int i = 0; i < 4; ++i)
    #pragma unroll
    for (int j = 0; j < 4; ++j) acc[i][j] = (f32x4){0.f, 0.f, 0.f, 0.f};

  kloop3(A, BT, Asm, Bsm, m0, n0, K, NKT, acc, tid, wm, wn, g, l15);

  // ---- epilogue: RoPE in-register, bf16 tile to LDS, packed chunk stores ----
  __syncthreads();
  const int bq = m0 >> 11;
  const int tg0 = m0 & 2047;
  const int type = (n0 < 2048) ? 0 : (n0 < 2560 ? 1 : 2);

  #pragma unroll
  for (int mi = 0; mi < 4; ++mi)
    #pragma unroll
    for (int r = 0; r < 4; ++r) {
      const int tl = wm * 64 + mi * 16 + g * 4 + r;
      const int t = tg0 + tl;
      #pragma unroll
      for (int ni = 0; ni < 4; ++ni) {
        const int cl = wn * 64 + ni * 16 + l15;
        float val = acc[mi][ni][r];
        float outv;
        if (type < 2) {
          float pairv = acc[mi][ni ^ 2][r];
          float2 cs = tab[t * 32 + (ni & 1) * 16 + l15];
          outv = (ni & 2) ? (val * cs.x + pairv * cs.y) : (val * cs.x - pairv * cs.y);
          if (type == 0) outv *= 0.18033688011112042f;
        } else {
          outv = val;
        }
        Ot[tl * 132 + cl] = f2bf(outv);
      }
    }
  __syncthreads();

  #pragma unroll
  for (int it = 0; it < 8; ++it) {
    const int id = wv * 8 + it;
    const int hl = id >> 4, q4 = (id >> 2) & 3, fi = id & 3;
    const int tile = (tg0 >> 5) + q4;
    if (type < 2) {
      const ushort* srow = Ot + (q4 * 32 + l31) * 132 + hl * 64 + fi * 16 + hi * 8;
      union { s16x4 h[2]; s16x8 v; } u;
      u.h[0] = *(const s16x4*)srow;
      u.h[1] = *(const s16x4*)(srow + 4);
      ushort* dst;
      if (type == 0) {
        const int h = (n0 >> 6) + hl;
        dst = Qp + (((size_t)(bq * 32 + h) * 64 + tile) * 4 + fi) * 512 + ln * 8;
      } else {
        const int h = ((n0 - 2048) >> 6) + hl;
        dst = Kp + (((size_t)(bq * 8 + h) * 64 + tile) * 4 + fi) * 512 + ln * 8;
      }
      *(s16x8*)dst = u.v;
    } else {
      const int hk = ((n0 - 2560) >> 6) + hl;
      const int col = hl * 64 + (fi & 1) * 32 + l31;
      const int row0 = q4 * 32 + (fi >> 1) * 16 + hi * 8;
      ushort o[8];
      #pragma unroll
      for (int j = 0; j < 8; ++j) o[j] = Ot[(row0 + j) * 132 + col];
      ushort* dst = Vp + (((size_t)(bq * 8 + hk) * 64 + tile) * 4 + fi) * 512 + ln * 8;
      *(s16x8*)dst = *(const s16x8*)o;
    }
  }
}

// ---------------- Wo GEMM: 128x128 tile, single-barrier engine, f32 store (r11) ----------------
__global__ __launch_bounds__(256) void gemm_bt_3b(const ushort* __restrict__ A,
                                                  const ushort* __restrict__ BT,
                                                  float* __restrict__ C, int M, int N, int K) {
  __shared__ __attribute__((aligned(128))) ushort smem[40960];   // 80 KiB
  ushort* Asm = smem;
  ushort* Bsm = smem + 16384;

  const int tid = threadIdx.x;
  const int ln = tid & 63, wv = tid >> 6;
  const int g = ln >> 4, l15 = ln & 15;
  const int wm = wv >> 1, wn = wv & 1;
  const int m0 = blockIdx.y * 128, n0 = blockIdx.x * 128;
  const int NKT = K / 64;

  f32x4 acc[4][4];
  #pragma unroll
  for (int i = 0; i < 4; ++i)
    #pragma unroll
    for (int j = 0; j < 4; ++j) acc[i][j] = (f32x4){0.f, 0.f, 0.f, 0.f};

  kloop3(A, BT, Asm, Bsm, m0, n0, K, NKT, acc, tid, wm, wn, g, l15);

  #pragma unroll
  for (int mi = 0; mi < 4; ++mi)
    #pragma unroll
    for (int r = 0; r < 4; ++r) {
      int row = m0 + wm * 64 + mi * 16 + g * 4 + r;
      float* crow = C + (size_t)row * N + n0 + wn * 64 + l15;
      #pragma unroll
      for (int ni = 0; ni < 4; ++ni) crow[ni * 16] = acc[mi][ni][r];
    }
}

// ---------------- causal GQA flash attention ----------------
// Round 17: triangle-paired load balancing.  Round-16 showed attn is
// latency-exposed, not pipe-bound: VALUBusy fell 78->61% with NO time change,
// and OccupancyPercent ~18% (avg 5.9 waves/CU resident vs 16 launched) —
// short-qtile waves drain out and the dispatch tails off at low parallelism.
// Fix: each wave processes q-tile pair (qA in [32,63], qB = 63-qA): every
// wave does exactly 65 K-tile iterations -> all waves finish together at a
// steady 8 waves/CU (2048 waves, 512 blocks, one dispatch pass).
// Per-segment body = round-16 kernel (MFMA row-sum lacc, defer-max,
// permlane pack) verbatim; waves stay barrier-free-independent.
__global__ __launch_bounds__(256) void attn_k(const ushort* __restrict__ Qp,
                                              const ushort* __restrict__ Kp,
                                              const ushort* __restrict__ Vp,
                                              ushort* __restrict__ O) {
  __shared__ ushort ep[4][32 * 64];
  const int tid = threadIdx.x, wv = tid >> 6, ln = tid & 63;
  const int l31 = ln & 31, hi = ln >> 5;

  const int f = blockIdx.x + gridDim.x * blockIdx.y;   // grid (16,32) -> 0..511
  const int xcd = f & 7, j = f >> 3;         // j: 0..63
  const int pr = xcd + 8 * (j & 1);          // (b,hk) pair id, 0..15
  const int b = pr >> 3, hk = pr & 7;
  const int s = j >> 1;                      // 0..31
  const int hq = hk * 4 + (s & 3);
  const int qA = 63 - ((s >> 2) * 4 + wv);   // 32..63 (heavy segment first)

  const ushort* Qh    = Qp + ((size_t)(b * 32 + hq)) * (64 * 2048);
  const ushort* Kbase = Kp + ((size_t)(b * 8 + hk)) * (64 * 2048);
  const ushort* Vbase = Vp + ((size_t)(b * 8 + hk)) * (64 * 2048);
  ushort* lds = ep[wv];

  s16x8 ones;
  #pragma unroll
  for (int i = 0; i < 8; ++i) ones[i] = (short)0x3F80;   // bf16 1.0

  f32x16 z16;
  #pragma unroll
  for (int r = 0; r < 16; ++r) z16[r] = 0.f;

  #pragma unroll 1
  for (int seg = 0; seg < 2; ++seg) {
    const int qtile = seg ? (63 - qA) : qA;
    const int qw = qtile * 32;
    const int nt = qtile + 1;

    s16x8 qf[4];
    {
      const ushort* qp_ = Qh + (size_t)qtile * 2048 + ln * 8;
      #pragma unroll
      for (int ks = 0; ks < 4; ++ks) qf[ks] = *(const s16x8*)(qp_ + ks * 512);
    }

    f32x16 oacc[2], lacc;
    #pragma unroll
    for (int r = 0; r < 16; ++r) { oacc[0][r] = 0.f; oacc[1][r] = 0.f; lacc[r] = 0.f; }
    float m = -1e30f;

    const ushort* kp = Kbase + ln * 8;
    const ushort* vp = Vbase + ln * 8;

    s16x8 kf[4];
    #pragma unroll
    for (int ks = 0; ks < 4; ++ks) kf[ks] = *(const s16x8*)(kp + ks * 512);
    kp += 2048;

    s16x8 vc[4];
    union pfu { unsigned u[4]; s16x8 v; };
    pfu pf0, pf1;

    #pragma unroll 1
    for (int kt = 0; kt < nt; ++kt) {
      if (kt) {
        __builtin_amdgcn_s_setprio(1);
        oacc[0] = __builtin_amdgcn_mfma_f32_32x32x16_bf16(vc[0], pf0.v, oacc[0], 0, 0, 0);
        oacc[1] = __builtin_amdgcn_mfma_f32_32x32x16_bf16(vc[1], pf0.v, oacc[1], 0, 0, 0);
        oacc[0] = __builtin_amdgcn_mfma_f32_32x32x16_bf16(vc[2], pf1.v, oacc[0], 0, 0, 0);
        oacc[1] = __builtin_amdgcn_mfma_f32_32x32x16_bf16(vc[3], pf1.v, oacc[1], 0, 0, 0);
        lacc    = __builtin_amdgcn_mfma_f32_32x32x16_bf16(ones,  pf0.v, lacc,    0, 0, 0);
        lacc    = __builtin_amdgcn_mfma_f32_32x32x16_bf16(ones,  pf1.v, lacc,    0, 0, 0);
        __builtin_amdgcn_s_setprio(0);
      }
      #pragma unroll
      for (int fi2 = 0; fi2 < 4; ++fi2) vc[fi2] = *(const s16x8*)(vp + fi2 * 512);
      vp += 2048;

      __builtin_amdgcn_s_setprio(1);
      f32x16 sp = __builtin_amdgcn_mfma_f32_32x32x16_bf16(kf[0], qf[0], z16, 0, 0, 0);
      sp = __builtin_amdgcn_mfma_f32_32x32x16_bf16(kf[1], qf[1], sp, 0, 0, 0);
      sp = __builtin_amdgcn_mfma_f32_32x32x16_bf16(kf[2], qf[2], sp, 0, 0, 0);
      sp = __builtin_amdgcn_mfma_f32_32x32x16_bf16(kf[3], qf[3], sp, 0, 0, 0);
      __builtin_amdgcn_s_setprio(0);

      if (kt + 1 < nt) {
        #pragma unroll
        for (int ks = 0; ks < 4; ++ks) kf[ks] = *(const s16x8*)(kp + ks * 512);
        kp += 2048;
      }

      if (kt == qtile) {
        #pragma unroll
        for (int r = 0; r < 16; ++r) {
          int key = (r & 3) + 8 * (r >> 2) + 4 * hi;
          if (key > l31) sp[r] = -1e30f;
        }
      }

      float t0 = fmaxf(fmaxf(sp[0], sp[1]), sp[2]);
      float t1 = fmaxf(fmaxf(sp[3], sp[4]), sp[5]);
      float t2 = fmaxf(fmaxf(sp[6], sp[7]), sp[8]);
      float t3 = fmaxf(fmaxf(sp[9], sp[10]), sp[11]);
      float t4 = fmaxf(fmaxf(sp[12], sp[13]), sp[14]);
      float u0 = fmaxf(fmaxf(t0, t1), t2);
      float u1 = fmaxf(fmaxf(t3, t4), sp[15]);
      float pm = plswap_max(fmaxf(u0, u1));

      // T13 defer-max: rescale only when some q-row grew by > 8 (exp2 domain).
      if (__any(pm - m > 8.0f)) {
        float mn = fmaxf(m, pm);
        float alpha = __builtin_amdgcn_exp2f(m - mn);
        m = mn;
        #pragma unroll
        for (int r = 0; r < 16; ++r) {
          oacc[0][r] *= alpha; oacc[1][r] *= alpha; lacc[r] *= alpha;
        }
      }

      #pragma unroll
      for (int r = 0; r < 16; ++r) sp[r] = __builtin_amdgcn_exp2f(sp[r] - m);

      unsigned cw[8];
      #pragma unroll
      for (int jj = 0; jj < 8; ++jj) {
        union { __hip_bfloat162 h; unsigned u; } pk;
        pk.h = __float22bfloat162_rn(make_float2(sp[2 * jj], sp[2 * jj + 1]));
        cw[jj] = pk.u;
      }
      {
        u32x2 r;
        r = __builtin_amdgcn_permlane32_swap(cw[0], cw[2], false, false);
        pf0.u[0] = r[0]; pf0.u[2] = r[1];
        r = __builtin_amdgcn_permlane32_swap(cw[1], cw[3], false, false);
        pf0.u[1] = r[0]; pf0.u[3] = r[1];
        r = __builtin_amdgcn_permlane32_swap(cw[4], cw[6], false, false);
        pf1.u[0] = r[0]; pf1.u[2] = r[1];
        r = __builtin_amdgcn_permlane32_swap(cw[5], cw[7], false, false);
        pf1.u[1] = r[0]; pf1.u[3] = r[1];
      }
    }

    __builtin_amdgcn_s_setprio(1);
    oacc[0] = __builtin_amdgcn_mfma_f32_32x32x16_bf16(vc[0], pf0.v, oacc[0], 0, 0, 0);
    oacc[1] = __builtin_amdgcn_mfma_f32_32x32x16_bf16(vc[1], pf0.v, oacc[1], 0, 0, 0);
    oacc[0] = __builtin_amdgcn_mfma_f32_32x32x16_bf16(vc[2], pf1.v, oacc[0], 0, 0, 0);
    oacc[1] = __builtin_amdgcn_mfma_f32_32x32x16_bf16(vc[3], pf1.v, oacc[1], 0, 0, 0);
    lacc    = __builtin_amdgcn_mfma_f32_32x32x16_bf16(ones,  pf0.v, lacc,    0, 0, 0);
    lacc    = __builtin_amdgcn_mfma_f32_32x32x16_bf16(ones,  pf1.v, lacc,    0, 0, 0);
    __builtin_amdgcn_s_setprio(0);

    float invl = 1.0f / lacc[0];
    #pragma unroll
    for (int dt = 0; dt < 2; ++dt)
      #pragma unroll
      for (int r = 0; r < 16; ++r) {
        int d = dt * 32 + (r & 3) + 8 * (r >> 2) + 4 * hi;
        int byte = (l31 * 128 + d * 2) ^ ((l31 & 7) << 4);
        *(ushort*)((char*)lds + byte) = f2bf(oacc[dt][r] * invl);
      }
    const int qr = ln >> 1, half = ln & 1;
    #pragma unroll
    for (int jj = 0; jj < 4; ++jj) {
      int byte = (qr * 128 + half * 64 + jj * 16) ^ ((qr & 7) << 4);
      s16x8 vrow = *(const s16x8*)((const char*)lds + byte);
      *(s16x8*)(O + ((size_t)(b * 2048 + qw + qr)) * 2048 + hq * 64 + half * 32 + jj * 8) = vrow;
    }
  }
}

extern "C" void kernel_launch(void* const* d_in, const int* in_sizes, int n_in,
                              void* d_out, int out_size, void* d_ws, size_t ws_size,
                              hipStream_t stream) {
  const float* x   = (const float*)d_in[0];
  const float* Wq  = (const float*)d_in[1];
  const float* Wkv = (const float*)d_in[2];
  const float* Wo  = (const float*)d_in[3];
  float* out = (float*)d_out;

  char* ws = (char*)d_ws;
  ushort* xb     = (ushort*)(ws);                 // 16 MiB  x bf16 (4096x2048)
  ushort* WqkvT  = (ushort*)(ws + 16777216);      // 12 MiB  [Wq|Wkv]^T bf16 (3072x2048)
  ushort* WoT    = (ushort*)(ws + 29360128);      //  8 MiB  Wo^T bf16 (2048x2048)
  float2* tab    = (float2*)(ws + 37748736);      // 512 KiB rope tables
  ushort* Qp     = (ushort*)(ws + 38273024);      // 16 MiB  Q packed
  ushort* Kp     = (ushort*)(ws + 55050240);      //  4 MiB  K packed
  ushort* Vp     = (ushort*)(ws + 59244544);      //  4 MiB  V packed
  ushort* Ob     = (ushort*)(ws + 63438848);      // 16 MiB  attn out bf16 (4096x2048)

  preamble_k<<<11008, 256, 0, stream>>>(x, Wq, Wkv, Wo, xb, WqkvT, WoT, tab);
  gemm_qkv_3b<<<dim3(24, 32), 256, 0, stream>>>(xb, WqkvT, tab, Qp, Kp, Vp);
  attn_k<<<dim3(16, 32), 256, 0, stream>>>(Qp, Kp, Vp, Ob);
  gemm_bt_3b<<<dim3(16, 32), 256, 0, stream>>>(Ob, WoT, out, 4096, 2048, 2048);
}

// Round 18
// 204.141 us; speedup vs baseline: 1.0788x; 1.0788x over previous
//
#include <hip/hip_runtime.h>
#include <hip/hip_bf16.h>

#define DEVI __device__ __forceinline__

typedef __attribute__((ext_vector_type(4))) float f32x4;
typedef __attribute__((ext_vector_type(16))) float f32x16;
typedef __attribute__((ext_vector_type(8))) short s16x8;
typedef __attribute__((ext_vector_type(4))) short s16x4;
typedef __attribute__((ext_vector_type(2))) unsigned u32x2;

DEVI ushort f2bf(float f) {
  union { float f; unsigned u; } v; v.f = f;
  unsigned r = v.u + 0x7FFFu + ((v.u >> 16) & 1u);
  return (ushort)(r >> 16);
}

DEVI void gload_lds16(const void* g, void* l) {
  __builtin_amdgcn_global_load_lds((const __attribute__((address_space(1))) void*)g,
                                   (__attribute__((address_space(3))) void*)l, 16, 0, 0);
}

#define MFMA16 __builtin_amdgcn_mfma_f32_16x16x32_bf16
#define SBAR() __builtin_amdgcn_s_barrier()
#define LGKM0() asm volatile("s_waitcnt lgkmcnt(0)")

// Cross-half (lane i <-> lane i+32) exchange via the permlane32_swap BUILTIN
// (round-10 lesson: inline-asm "+v","+v" self-swap corrupted the row max).
DEVI float plswap_max(float x) {
  union { float f; unsigned u; } a; a.f = x;
  u32x2 r = __builtin_amdgcn_permlane32_swap(a.u, a.u, false, false);
  union { unsigned u; float f; } o0, o1; o0.u = r[0]; o1.u = r[1];
  return fmaxf(o0.f, o1.f);
}
DEVI float plswap_sum(float x) {
  union { float f; unsigned u; } a; a.f = x;
  u32x2 r = __builtin_amdgcn_permlane32_swap(a.u, a.u, false, false);
  union { unsigned u; float f; } o0, o1; o0.u = r[0]; o1.u = r[1];
  return o0.f + o1.f;
}

// ---- BK=64 staging/frag (rows of 64 bf16 = 8 chunks), swizzle c ^ (row&7) ----
DEVI void stage128q(const ushort* __restrict__ gsrc, int K, ushort* ld, int tid) {
  #pragma unroll
  for (int j = 0; j < 4; ++j) {
    const int ci = j * 256 + tid;
    const int row = ci >> 3, c = ci & 7;
    gload_lds16(gsrc + (size_t)row * K + ((c ^ (row & 7)) << 3),
                ld + (size_t)(j * 256 + (tid & ~63)) * 8);
  }
}
DEVI s16x8 ldfrag(const ushort* tile, int row, int kc) {
  return *(const s16x8*)((const char*)tile + row * 128 + ((kc ^ (row & 7)) << 4));
}

// =====================================================================
// Single-barrier triple-B K-loop, BK=64, BM=BN=128 (champion engine).
// =====================================================================
DEVI void kloop3(const ushort* __restrict__ A, const ushort* __restrict__ BT,
                 ushort* Asm, ushort* Bsm, int m0, int n0, int K, int NKT,
                 f32x4 (&acc)[4][4], int tid, int wm, int wn, int g, int l15) {
  stage128q(A + (size_t)m0 * K, K, Asm, tid);
  stage128q(BT + (size_t)n0 * K, K, Bsm, tid);
  stage128q(BT + (size_t)n0 * K + 64, K, Bsm + 8192, tid);
  asm volatile("s_waitcnt vmcnt(4)");
  SBAR();

  int rd = 0;
  #pragma unroll 1
  for (int t = 0; t < NKT; ++t) {
    const ushort* Ah = Asm + (t & 1) * 8192;
    const ushort* Bh = Bsm + rd * 8192;
    s16x8 af[4][2], bfr[4][2];

    #pragma unroll
    for (int ks = 0; ks < 2; ++ks) {
      #pragma unroll
      for (int ni = 0; ni < 4; ++ni)
        bfr[ni][ks] = ldfrag(Bh, wn * 64 + ni * 16 + l15, ks * 4 + g);
      #pragma unroll
      for (int mi = 0; mi < 4; ++mi)
        af[mi][ks] = ldfrag(Ah, wm * 64 + mi * 16 + l15, ks * 4 + g);
    }
    if (t + 1 < NKT)
      stage128q(A + (size_t)m0 * K + (t + 1) * 64, K, Asm + ((t + 1) & 1) * 8192, tid);
    int wr = rd + 2; if (wr >= 3) wr -= 3;
    if (t + 2 < NKT)
      stage128q(BT + (size_t)n0 * K + (t + 2) * 64, K, Bsm + wr * 8192, tid);

    LGKM0();
    __builtin_amdgcn_sched_barrier(0);
    __builtin_amdgcn_s_setprio(1);
    #pragma unroll
    for (int mi = 0; mi < 4; ++mi)
      #pragma unroll
      for (int ni = 0; ni < 2; ++ni)
        #pragma unroll
        for (int ks = 0; ks < 2; ++ks)
          acc[mi][ni] = MFMA16(af[mi][ks], bfr[ni][ks], acc[mi][ni], 0, 0, 0);
    #pragma unroll
    for (int mi = 0; mi < 4; ++mi)
      #pragma unroll
      for (int ni = 0; ni < 2; ++ni)
        #pragma unroll
        for (int ks = 0; ks < 2; ++ks)
          acc[mi][2 + ni] = MFMA16(af[mi][ks], bfr[2 + ni][ks], acc[mi][2 + ni], 0, 0, 0);
    __builtin_amdgcn_s_setprio(0);

    if (t + 2 < NKT)      asm volatile("s_waitcnt vmcnt(4)");
    else if (t + 1 < NKT) asm volatile("s_waitcnt vmcnt(0)");
    SBAR();
    rd = (rd == 2) ? 0 : rd + 1;
  }
}

// =====================================================================
// Fused preamble (round-15 win).
// =====================================================================
__global__ __launch_bounds__(256) void preamble_k(const float* __restrict__ x,
                                                  const float* __restrict__ Wq,
                                                  const float* __restrict__ Wkv,
                                                  const float* __restrict__ Wo,
                                                  ushort* __restrict__ xb,
                                                  ushort* __restrict__ WqkvT,
                                                  ushort* __restrict__ WoT,
                                                  float2* __restrict__ tab) {
  const int id = blockIdx.x;
  const int tid = threadIdx.x;

  if (id >= 2560) {
    if (id < 10752) {                       // ---- elementwise cast ----
      const int lid = id - 2560;
      int i = (lid * 256 + tid) * 4;
      float4 v = *(const float4*)(x + i);
      ushort4 o;
      o.x = f2bf(v.x); o.y = f2bf(v.y); o.z = f2bf(v.z); o.w = f2bf(v.w);
      *(ushort4*)(xb + i) = o;
    } else {                                // ---- rope tables ----
      const int lid = id - 10752;
      int idx = lid * 256 + tid;            // T*32 = 65536
      int t = idx >> 5, i = idx & 31;
      float inv = expf(-(float)i * 0.28782313662425575f);  // ln(10000)/32
      float ang = (float)t * inv;
      tab[idx] = make_float2(cosf(ang), sinf(ang));
    }
    return;
  }

  // ---- transpose+cast branch ----
  __shared__ ushort tile[64][66];
  const float* in; ushort* out; int R, C, bx, by;
  if (id < 1024)        { in = Wq;  out = WqkvT;              R = 2048; C = 2048; bx = id & 31;          by = id >> 5; }
  else if (id < 1536)   { in = Wkv; out = WqkvT + 2048*2048;  R = 2048; C = 1024; bx = (id-1024) & 15;   by = (id-1024) >> 4; }
  else                  { in = Wo;  out = WoT;                R = 2048; C = 2048; bx = (id-1536) & 31;   by = (id-1536) >> 5; }
  const int r0 = by * 64, c0 = bx * 64;
  #pragma unroll
  for (int j = 0; j < 16; ++j) {
    int idx = j * 256 + tid;
    int r = idx >> 6, c = idx & 63;
    tile[c][r] = f2bf(in[(size_t)(r0 + r) * C + c0 + c]);
  }
  __syncthreads();
  #pragma unroll
  for (int j = 0; j < 16; ++j) {
    int idx = j * 256 + tid;
    int c = idx >> 6, r = idx & 63;
    out[(size_t)(c0 + c) * R + r0 + r] = tile[c][r];
  }
}

// ---------------- fused QKV GEMM: 128x128 tile, single-barrier engine (r11) ----------------
__global__ __launch_bounds__(256) void gemm_qkv_3b(const ushort* __restrict__ A,
                                                   const ushort* __restrict__ BT,
                                                   const float2* __restrict__ tab,
                                                   ushort* __restrict__ Qp,
                                                   ushort* __restrict__ Kp,
                                                   ushort* __restrict__ Vp) {
  constexpr int K = 2048, NKT = 32;
  __shared__ __attribute__((aligned(128))) ushort smem[40960];   // 80 KiB
  ushort* Asm = smem;            // [2][128*64]
  ushort* Bsm = smem + 16384;    // [3][128*64]
  ushort* Ot = smem;             // epilogue tile [128][132]

  const int tid = threadIdx.x;
  const int ln = tid & 63, wv = tid >> 6;
  const int g = ln >> 4, l15 = ln & 15, l31 = ln & 31, hi = ln >> 5;
  const int wm = wv >> 1, wn = wv & 1;
  const int m0 = blockIdx.y * 128, n0 = blockIdx.x * 128;

  f32x4 acc[4][4];
  #pragma unroll
  for (int i = 0; i < 4; ++i)
    #pragma unroll
    for (int j = 0; j < 4; ++j) acc[i][j] = (f32x4){0.f, 0.f, 0.f, 0.f};

  kloop3(A, BT, Asm, Bsm, m0, n0, K, NKT, acc, tid, wm, wn, g, l15);

  // ---- epilogue: RoPE in-register, bf16 tile to LDS, packed chunk stores ----
  __syncthreads();
  const int bq = m0 >> 11;
  const int tg0 = m0 & 2047;
  const int type = (n0 < 2048) ? 0 : (n0 < 2560 ? 1 : 2);

  #pragma unroll
  for (int mi = 0; mi < 4; ++mi)
    #pragma unroll
    for (int r = 0; r < 4; ++r) {
      const int tl = wm * 64 + mi * 16 + g * 4 + r;
      const int t = tg0 + tl;
      #pragma unroll
      for (int ni = 0; ni < 4; ++ni) {
        const int cl = wn * 64 + ni * 16 + l15;
        float val = acc[mi][ni][r];
        float outv;
        if (type < 2) {
          float pairv = acc[mi][ni ^ 2][r];
          float2 cs = tab[t * 32 + (ni & 1) * 16 + l15];
          outv = (ni & 2) ? (val * cs.x + pairv * cs.y) : (val * cs.x - pairv * cs.y);
          if (type == 0) outv *= 0.18033688011112042f;
        } else {
          outv = val;
        }
        Ot[tl * 132 + cl] = f2bf(outv);
      }
    }
  __syncthreads();

  #pragma unroll
  for (int it = 0; it < 8; ++it) {
    const int id = wv * 8 + it;
    const int hl = id >> 4, q4 = (id >> 2) & 3, fi = id & 3;
    const int tile = (tg0 >> 5) + q4;
    if (type < 2) {
      const ushort* srow = Ot + (q4 * 32 + l31) * 132 + hl * 64 + fi * 16 + hi * 8;
      union { s16x4 h[2]; s16x8 v; } u;
      u.h[0] = *(const s16x4*)srow;
      u.h[1] = *(const s16x4*)(srow + 4);
      ushort* dst;
      if (type == 0) {
        const int h = (n0 >> 6) + hl;
        dst = Qp + (((size_t)(bq * 32 + h) * 64 + tile) * 4 + fi) * 512 + ln * 8;
      } else {
        const int h = ((n0 - 2048) >> 6) + hl;
        dst = Kp + (((size_t)(bq * 8 + h) * 64 + tile) * 4 + fi) * 512 + ln * 8;
      }
      *(s16x8*)dst = u.v;
    } else {
      const int hk = ((n0 - 2560) >> 6) + hl;
      const int col = hl * 64 + (fi & 1) * 32 + l31;
      const int row0 = q4 * 32 + (fi >> 1) * 16 + hi * 8;
      ushort o[8];
      #pragma unroll
      for (int j = 0; j < 8; ++j) o[j] = Ot[(row0 + j) * 132 + col];
      ushort* dst = Vp + (((size_t)(bq * 8 + hk) * 64 + tile) * 4 + fi) * 512 + ln * 8;
      *(s16x8*)dst = *(const s16x8*)o;
    }
  }
}

// ---------------- Wo GEMM: 128x128 tile, single-barrier engine, f32 store (r11) ----------------
__global__ __launch_bounds__(256) void gemm_bt_3b(const ushort* __restrict__ A,
                                                  const ushort* __restrict__ BT,
                                                  float* __restrict__ C, int M, int N, int K) {
  __shared__ __attribute__((aligned(128))) ushort smem[40960];   // 80 KiB
  ushort* Asm = smem;
  ushort* Bsm = smem + 16384;

  const int tid = threadIdx.x;
  const int ln = tid & 63, wv = tid >> 6;
  const int g = ln >> 4, l15 = ln & 15;
  const int wm = wv >> 1, wn = wv & 1;
  const int m0 = blockIdx.y * 128, n0 = blockIdx.x * 128;
  const int NKT = K / 64;

  f32x4 acc[4][4];
  #pragma unroll
  for (int i = 0; i < 4; ++i)
    #pragma unroll
    for (int j = 0; j < 4; ++j) acc[i][j] = (f32x4){0.f, 0.f, 0.f, 0.f};

  kloop3(A, BT, Asm, Bsm, m0, n0, K, NKT, acc, tid, wm, wn, g, l15);

  #pragma unroll
  for (int mi = 0; mi < 4; ++mi)
    #pragma unroll
    for (int r = 0; r < 4; ++r) {
      int row = m0 + wm * 64 + mi * 16 + g * 4 + r;
      float* crow = C + (size_t)row * N + n0 + wn * 64 + l15;
      #pragma unroll
      for (int ni = 0; ni < 4; ++ni) crow[ni * 16] = acc[mi][ni][r];
    }
}

// ---------------- causal GQA flash attention ----------------
// Round 18: ONE-WAVE workgroups with hardware backfill.  Round-16/17 data:
// attn is latency-exposed (VALU cut -> no time change) and the fix must RAISE
// resident waves.  r17's pairing halved launched parallelism (occupancy
// 18->10.8%, +VGPR) and regressed.  Here: 4096 single-wave blocks (64 thr,
// 4 KB LDS, r15 body = VGPR 84).  The CU scheduler retires each wave
// independently and backfills from the 4096-deep queue -> sustained ~16
// blocks/CU instead of the 4-wave-block decay-to-2 tail.  LJF preserved
// (qtile descends with dispatch order).  Body = round-15 attn verbatim.
__global__ __launch_bounds__(64) void attn_k(const ushort* __restrict__ Qp,
                                             const ushort* __restrict__ Kp,
                                             const ushort* __restrict__ Vp,
                                             ushort* __restrict__ O) {
  __shared__ ushort ep[32 * 64];      // one epilogue transpose patch (4 KB)
  const int ln = threadIdx.x & 63;
  const int l31 = ln & 31, hi = ln >> 5;

  const int f = blockIdx.x;                  // 0..4095, one wave per block
  const int xcd = f & 7, j = f >> 3;         // j: 0..511
  const int pr = xcd + 8 * (j & 1);          // (b,hk) pair id, 0..15
  const int b = pr >> 3, hk = pr & 7;
  const int s = j >> 1;                      // 0..255
  const int hq = hk * 4 + (s & 3);
  const int qtile = 63 - (s >> 2);           // LJF: early blocks get long jobs
  const int qw = qtile * 32;
  const int nt = qtile + 1;

  const ushort* Qh    = Qp + ((size_t)(b * 32 + hq)) * (64 * 2048);
  const ushort* Kbase = Kp + ((size_t)(b * 8 + hk)) * (64 * 2048);
  const ushort* Vbase = Vp + ((size_t)(b * 8 + hk)) * (64 * 2048);
  ushort* lds = ep;

  s16x8 qf[4];
  {
    const ushort* qp_ = Qh + (size_t)qtile * 2048 + ln * 8;
    #pragma unroll
    for (int ks = 0; ks < 4; ++ks) qf[ks] = *(const s16x8*)(qp_ + ks * 512);
  }

  f32x16 z16;
  #pragma unroll
  for (int r = 0; r < 16; ++r) z16[r] = 0.f;

  f32x16 oacc[2];
  #pragma unroll
  for (int dt = 0; dt < 2; ++dt)
    #pragma unroll
    for (int r = 0; r < 16; ++r) oacc[dt][r] = 0.f;
  float m = -1e30f, l = 0.f;

  const ushort* kp = Kbase + ln * 8;
  const ushort* vp = Vbase + ln * 8;

  s16x8 kf[4];
  #pragma unroll
  for (int ks = 0; ks < 4; ++ks) kf[ks] = *(const s16x8*)(kp + ks * 512);
  kp += 2048;

  s16x8 vc[4];
  union pfu { unsigned u[4]; s16x8 v; };
  pfu pf0, pf1;

  #pragma unroll 1
  for (int kt = 0; kt < nt; ++kt) {
    if (kt) {
      __builtin_amdgcn_s_setprio(1);
      oacc[0] = __builtin_amdgcn_mfma_f32_32x32x16_bf16(vc[0], pf0.v, oacc[0], 0, 0, 0);
      oacc[1] = __builtin_amdgcn_mfma_f32_32x32x16_bf16(vc[1], pf0.v, oacc[1], 0, 0, 0);
      oacc[0] = __builtin_amdgcn_mfma_f32_32x32x16_bf16(vc[2], pf1.v, oacc[0], 0, 0, 0);
      oacc[1] = __builtin_amdgcn_mfma_f32_32x32x16_bf16(vc[3], pf1.v, oacc[1], 0, 0, 0);
      __builtin_amdgcn_s_setprio(0);
    }
    #pragma unroll
    for (int fi2 = 0; fi2 < 4; ++fi2) vc[fi2] = *(const s16x8*)(vp + fi2 * 512);
    vp += 2048;

    __builtin_amdgcn_s_setprio(1);
    f32x16 sp = __builtin_amdgcn_mfma_f32_32x32x16_bf16(kf[0], qf[0], z16, 0, 0, 0);
    sp = __builtin_amdgcn_mfma_f32_32x32x16_bf16(kf[1], qf[1], sp, 0, 0, 0);
    sp = __builtin_amdgcn_mfma_f32_32x32x16_bf16(kf[2], qf[2], sp, 0, 0, 0);
    sp = __builtin_amdgcn_mfma_f32_32x32x16_bf16(kf[3], qf[3], sp, 0, 0, 0);
    __builtin_amdgcn_s_setprio(0);

    if (kt + 1 < nt) {
      #pragma unroll
      for (int ks = 0; ks < 4; ++ks) kf[ks] = *(const s16x8*)(kp + ks * 512);
      kp += 2048;
    }

    if (kt == qtile) {
      #pragma unroll
      for (int r = 0; r < 16; ++r) {
        int key = (r & 3) + 8 * (r >> 2) + 4 * hi;
        if (key > l31) sp[r] = -1e30f;
      }
    }

    float t0 = fmaxf(fmaxf(sp[0], sp[1]), sp[2]);
    float t1 = fmaxf(fmaxf(sp[3], sp[4]), sp[5]);
    float t2 = fmaxf(fmaxf(sp[6], sp[7]), sp[8]);
    float t3 = fmaxf(fmaxf(sp[9], sp[10]), sp[11]);
    float t4 = fmaxf(fmaxf(sp[12], sp[13]), sp[14]);
    float u0 = fmaxf(fmaxf(t0, t1), t2);
    float u1 = fmaxf(fmaxf(t3, t4), sp[15]);
    float pm = plswap_max(fmaxf(u0, u1));

    // T13 defer-max: rescale only when some q-row grew by > 8 (exp2 domain).
    if (__any(pm - m > 8.0f)) {
      float mn = fmaxf(m, pm);
      float alpha = __builtin_amdgcn_exp2f(m - mn);
      m = mn;
      l *= alpha;
      #pragma unroll
      for (int dt = 0; dt < 2; ++dt)
        #pragma unroll
        for (int r = 0; r < 16; ++r) oacc[dt][r] *= alpha;
    }

    #pragma unroll
    for (int r = 0; r < 16; ++r) sp[r] = __builtin_amdgcn_exp2f(sp[r] - m);
    {
      float a0 = sp[0] + sp[1], a1 = sp[2] + sp[3], a2 = sp[4] + sp[5], a3 = sp[6] + sp[7];
      float a4 = sp[8] + sp[9], a5 = sp[10] + sp[11], a6 = sp[12] + sp[13], a7 = sp[14] + sp[15];
      float b0 = a0 + a1, b1 = a2 + a3, b2 = a4 + a5, b3 = a6 + a7;
      l += plswap_sum((b0 + b1) + (b2 + b3));
    }

    unsigned cw[8];
    #pragma unroll
    for (int jj = 0; jj < 8; ++jj) {
      union { __hip_bfloat162 h; unsigned u; } pk;
      pk.h = __float22bfloat162_rn(make_float2(sp[2 * jj], sp[2 * jj + 1]));
      cw[jj] = pk.u;
    }
    {
      u32x2 r;
      r = __builtin_amdgcn_permlane32_swap(cw[0], cw[2], false, false);
      pf0.u[0] = r[0]; pf0.u[2] = r[1];
      r = __builtin_amdgcn_permlane32_swap(cw[1], cw[3], false, false);
      pf0.u[1] = r[0]; pf0.u[3] = r[1];
      r = __builtin_amdgcn_permlane32_swap(cw[4], cw[6], false, false);
      pf1.u[0] = r[0]; pf1.u[2] = r[1];
      r = __builtin_amdgcn_permlane32_swap(cw[5], cw[7], false, false);
      pf1.u[1] = r[0]; pf1.u[3] = r[1];
    }
  }

  __builtin_amdgcn_s_setprio(1);
  oacc[0] = __builtin_amdgcn_mfma_f32_32x32x16_bf16(vc[0], pf0.v, oacc[0], 0, 0, 0);
  oacc[1] = __builtin_amdgcn_mfma_f32_32x32x16_bf16(vc[1], pf0.v, oacc[1], 0, 0, 0);
  oacc[0] = __builtin_amdgcn_mfma_f32_32x32x16_bf16(vc[2], pf1.v, oacc[0], 0, 0, 0);
  oacc[1] = __builtin_amdgcn_mfma_f32_32x32x16_bf16(vc[3], pf1.v, oacc[1], 0, 0, 0);
  __builtin_amdgcn_s_setprio(0);

  float invl = 1.0f / l;
  #pragma unroll
  for (int dt = 0; dt < 2; ++dt)
    #pragma unroll
    for (int r = 0; r < 16; ++r) {
      int d = dt * 32 + (r & 3) + 8 * (r >> 2) + 4 * hi;
      int byte = (l31 * 128 + d * 2) ^ ((l31 & 7) << 4);
      *(ushort*)((char*)lds + byte) = f2bf(oacc[dt][r] * invl);
    }
  const int qr = ln >> 1, half = ln & 1;
  #pragma unroll
  for (int jj = 0; jj < 4; ++jj) {
    int byte = (qr * 128 + half * 64 + jj * 16) ^ ((qr & 7) << 4);
    s16x8 vrow = *(const s16x8*)((const char*)lds + byte);
    *(s16x8*)(O + ((size_t)(b * 2048 + qw + qr)) * 2048 + hq * 64 + half * 32 + jj * 8) = vrow;
  }
}

extern "C" void kernel_launch(void* const* d_in, const int* in_sizes, int n_in,
                              void* d_out, int out_size, void* d_ws, size_t ws_size,
                              hipStream_t stream) {
  const float* x   = (const float*)d_in[0];
  const float* Wq  = (const float*)d_in[1];
  const float* Wkv = (const float*)d_in[2];
  const float* Wo  = (const float*)d_in[3];
  float* out = (float*)d_out;

  char* ws = (char*)d_ws;
  ushort* xb     = (ushort*)(ws);                 // 16 MiB  x bf16 (4096x2048)
  ushort* WqkvT  = (ushort*)(ws + 16777216);      // 12 MiB  [Wq|Wkv]^T bf16 (3072x2048)
  ushort* WoT    = (ushort*)(ws + 29360128);      //  8 MiB  Wo^T bf16 (2048x2048)
  float2* tab    = (float2*)(ws + 37748736);      // 512 KiB rope tables
  ushort* Qp     = (ushort*)(ws + 38273024);      // 16 MiB  Q packed
  ushort* Kp     = (ushort*)(ws + 55050240);      //  4 MiB  K packed
  ushort* Vp     = (ushort*)(ws + 59244544);      //  4 MiB  V packed
  ushort* Ob     = (ushort*)(ws + 63438848);      // 16 MiB  attn out bf16 (4096x2048)

  preamble_k<<<11008, 256, 0, stream>>>(x, Wq, Wkv, Wo, xb, WqkvT, WoT, tab);
  gemm_qkv_3b<<<dim3(24, 32), 256, 0, stream>>>(xb, WqkvT, tab, Qp, Kp, Vp);
  attn_k<<<4096, 64, 0, stream>>>(Qp, Kp, Vp, Ob);
  gemm_bt_3b<<<dim3(16, 32), 256, 0, stream>>>(Ob, WoT, out, 4096, 2048, 2048);
}

// Round 19
// 200.250 us; speedup vs baseline: 1.0998x; 1.0194x over previous
//
#include <hip/hip_runtime.h>
#include <hip/hip_bf16.h>

#define DEVI __device__ __forceinline__

typedef __attribute__((ext_vector_type(4))) float f32x4;
typedef __attribute__((ext_vector_type(16))) float f32x16;
typedef __attribute__((ext_vector_type(8))) short s16x8;
typedef __attribute__((ext_vector_type(4))) short s16x4;
typedef __attribute__((ext_vector_type(2))) unsigned u32x2;

DEVI ushort f2bf(float f) {
  union { float f; unsigned u; } v; v.f = f;
  unsigned r = v.u + 0x7FFFu + ((v.u >> 16) & 1u);
  return (ushort)(r >> 16);
}

DEVI void gload_lds16(const void* g, void* l) {
  __builtin_amdgcn_global_load_lds((const __attribute__((address_space(1))) void*)g,
                                   (__attribute__((address_space(3))) void*)l, 16, 0, 0);
}

#define MFMA16 __builtin_amdgcn_mfma_f32_16x16x32_bf16
#define MFMA32 __builtin_amdgcn_mfma_f32_32x32x16_bf16
#define SBAR() __builtin_amdgcn_s_barrier()
#define LGKM0() asm volatile("s_waitcnt lgkmcnt(0)")

// Cross-half (lane i <-> lane i+32) exchange via the permlane32_swap BUILTIN
// (round-10 lesson: inline-asm "+v","+v" self-swap corrupted the row max).
DEVI float plswap_max(float x) {
  union { float f; unsigned u; } a; a.f = x;
  u32x2 r = __builtin_amdgcn_permlane32_swap(a.u, a.u, false, false);
  union { unsigned u; float f; } o0, o1; o0.u = r[0]; o1.u = r[1];
  return fmaxf(o0.f, o1.f);
}
DEVI float plswap_sum(float x) {
  union { float f; unsigned u; } a; a.f = x;
  u32x2 r = __builtin_amdgcn_permlane32_swap(a.u, a.u, false, false);
  union { unsigned u; float f; } o0, o1; o0.u = r[0]; o1.u = r[1];
  return o0.f + o1.f;
}

// ---- BK=64 staging/frag (rows of 64 bf16 = 8 chunks), swizzle c ^ (row&7) ----
DEVI void stage128q(const ushort* __restrict__ gsrc, int K, ushort* ld, int tid) {
  #pragma unroll
  for (int j = 0; j < 4; ++j) {
    const int ci = j * 256 + tid;
    const int row = ci >> 3, c = ci & 7;
    gload_lds16(gsrc + (size_t)row * K + ((c ^ (row & 7)) << 3),
                ld + (size_t)(j * 256 + (tid & ~63)) * 8);
  }
}
DEVI s16x8 ldfrag(const ushort* tile, int row, int kc) {
  return *(const s16x8*)((const char*)tile + row * 128 + ((kc ^ (row & 7)) << 4));
}

// =====================================================================
// Single-barrier triple-B K-loop, BK=64, BM=BN=128 (champion engine).
// =====================================================================
DEVI void kloop3(const ushort* __restrict__ A, const ushort* __restrict__ BT,
                 ushort* Asm, ushort* Bsm, int m0, int n0, int K, int NKT,
                 f32x4 (&acc)[4][4], int tid, int wm, int wn, int g, int l15) {
  stage128q(A + (size_t)m0 * K, K, Asm, tid);
  stage128q(BT + (size_t)n0 * K, K, Bsm, tid);
  stage128q(BT + (size_t)n0 * K + 64, K, Bsm + 8192, tid);
  asm volatile("s_waitcnt vmcnt(4)");
  SBAR();

  int rd = 0;
  #pragma unroll 1
  for (int t = 0; t < NKT; ++t) {
    const ushort* Ah = Asm + (t & 1) * 8192;
    const ushort* Bh = Bsm + rd * 8192;
    s16x8 af[4][2], bfr[4][2];

    #pragma unroll
    for (int ks = 0; ks < 2; ++ks) {
      #pragma unroll
      for (int ni = 0; ni < 4; ++ni)
        bfr[ni][ks] = ldfrag(Bh, wn * 64 + ni * 16 + l15, ks * 4 + g);
      #pragma unroll
      for (int mi = 0; mi < 4; ++mi)
        af[mi][ks] = ldfrag(Ah, wm * 64 + mi * 16 + l15, ks * 4 + g);
    }
    if (t + 1 < NKT)
      stage128q(A + (size_t)m0 * K + (t + 1) * 64, K, Asm + ((t + 1) & 1) * 8192, tid);
    int wr = rd + 2; if (wr >= 3) wr -= 3;
    if (t + 2 < NKT)
      stage128q(BT + (size_t)n0 * K + (t + 2) * 64, K, Bsm + wr * 8192, tid);

    LGKM0();
    __builtin_amdgcn_sched_barrier(0);
    __builtin_amdgcn_s_setprio(1);
    #pragma unroll
    for (int mi = 0; mi < 4; ++mi)
      #pragma unroll
      for (int ni = 0; ni < 2; ++ni)
        #pragma unroll
        for (int ks = 0; ks < 2; ++ks)
          acc[mi][ni] = MFMA16(af[mi][ks], bfr[ni][ks], acc[mi][ni], 0, 0, 0);
    #pragma unroll
    for (int mi = 0; mi < 4; ++mi)
      #pragma unroll
      for (int ni = 0; ni < 2; ++ni)
        #pragma unroll
        for (int ks = 0; ks < 2; ++ks)
          acc[mi][2 + ni] = MFMA16(af[mi][ks], bfr[2 + ni][ks], acc[mi][2 + ni], 0, 0, 0);
    __builtin_amdgcn_s_setprio(0);

    if (t + 2 < NKT)      asm volatile("s_waitcnt vmcnt(4)");
    else if (t + 1 < NKT) asm volatile("s_waitcnt vmcnt(0)");
    SBAR();
    rd = (rd == 2) ? 0 : rd + 1;
  }
}

// =====================================================================
// Fused preamble (round-15 win).
// =====================================================================
__global__ __launch_bounds__(256) void preamble_k(const float* __restrict__ x,
                                                  const float* __restrict__ Wq,
                                                  const float* __restrict__ Wkv,
                                                  const float* __restrict__ Wo,
                                                  ushort* __restrict__ xb,
                                                  ushort* __restrict__ WqkvT,
                                                  ushort* __restrict__ WoT,
                                                  float2* __restrict__ tab) {
  const int id = blockIdx.x;
  const int tid = threadIdx.x;

  if (id >= 2560) {
    if (id < 10752) {                       // ---- elementwise cast ----
      const int lid = id - 2560;
      int i = (lid * 256 + tid) * 4;
      float4 v = *(const float4*)(x + i);
      ushort4 o;
      o.x = f2bf(v.x); o.y = f2bf(v.y); o.z = f2bf(v.z); o.w = f2bf(v.w);
      *(ushort4*)(xb + i) = o;
    } else {                                // ---- rope tables ----
      const int lid = id - 10752;
      int idx = lid * 256 + tid;            // T*32 = 65536
      int t = idx >> 5, i = idx & 31;
      float inv = expf(-(float)i * 0.28782313662425575f);  // ln(10000)/32
      float ang = (float)t * inv;
      tab[idx] = make_float2(cosf(ang), sinf(ang));
    }
    return;
  }

  // ---- transpose+cast branch ----
  __shared__ ushort tile[64][66];
  const float* in; ushort* out; int R, C, bx, by;
  if (id < 1024)        { in = Wq;  out = WqkvT;              R = 2048; C = 2048; bx = id & 31;          by = id >> 5; }
  else if (id < 1536)   { in = Wkv; out = WqkvT + 2048*2048;  R = 2048; C = 1024; bx = (id-1024) & 15;   by = (id-1024) >> 4; }
  else                  { in = Wo;  out = WoT;                R = 2048; C = 2048; bx = (id-1536) & 31;   by = (id-1536) >> 5; }
  const int r0 = by * 64, c0 = bx * 64;
  #pragma unroll
  for (int j = 0; j < 16; ++j) {
    int idx = j * 256 + tid;
    int r = idx >> 6, c = idx & 63;
    tile[c][r] = f2bf(in[(size_t)(r0 + r) * C + c0 + c]);
  }
  __syncthreads();
  #pragma unroll
  for (int j = 0; j < 16; ++j) {
    int idx = j * 256 + tid;
    int c = idx >> 6, r = idx & 63;
    out[(size_t)(c0 + c) * R + r0 + r] = tile[c][r];
  }
}

// ---------------- fused QKV GEMM: 128x128 tile, single-barrier engine (r11) ----------------
__global__ __launch_bounds__(256) void gemm_qkv_3b(const ushort* __restrict__ A,
                                                   const ushort* __restrict__ BT,
                                                   const float2* __restrict__ tab,
                                                   ushort* __restrict__ Qp,
                                                   ushort* __restrict__ Kp,
                                                   ushort* __restrict__ Vp) {
  constexpr int K = 2048, NKT = 32;
  __shared__ __attribute__((aligned(128))) ushort smem[40960];   // 80 KiB
  ushort* Asm = smem;            // [2][128*64]
  ushort* Bsm = smem + 16384;    // [3][128*64]
  ushort* Ot = smem;             // epilogue tile [128][132]

  const int tid = threadIdx.x;
  const int ln = tid & 63, wv = tid >> 6;
  const int g = ln >> 4, l15 = ln & 15, l31 = ln & 31, hi = ln >> 5;
  const int wm = wv >> 1, wn = wv & 1;
  const int m0 = blockIdx.y * 128, n0 = blockIdx.x * 128;

  f32x4 acc[4][4];
  #pragma unroll
  for (int i = 0; i < 4; ++i)
    #pragma unroll
    for (int j = 0; j < 4; ++j) acc[i][j] = (f32x4){0.f, 0.f, 0.f, 0.f};

  kloop3(A, BT, Asm, Bsm, m0, n0, K, NKT, acc, tid, wm, wn, g, l15);

  // ---- epilogue: RoPE in-register, bf16 tile to LDS, packed chunk stores ----
  __syncthreads();
  const int bq = m0 >> 11;
  const int tg0 = m0 & 2047;
  const int type = (n0 < 2048) ? 0 : (n0 < 2560 ? 1 : 2);

  #pragma unroll
  for (int mi = 0; mi < 4; ++mi)
    #pragma unroll
    for (int r = 0; r < 4; ++r) {
      const int tl = wm * 64 + mi * 16 + g * 4 + r;
      const int t = tg0 + tl;
      #pragma unroll
      for (int ni = 0; ni < 4; ++ni) {
        const int cl = wn * 64 + ni * 16 + l15;
        float val = acc[mi][ni][r];
        float outv;
        if (type < 2) {
          float pairv = acc[mi][ni ^ 2][r];
          float2 cs = tab[t * 32 + (ni & 1) * 16 + l15];
          outv = (ni & 2) ? (val * cs.x + pairv * cs.y) : (val * cs.x - pairv * cs.y);
          if (type == 0) outv *= 0.18033688011112042f;
        } else {
          outv = val;
        }
        Ot[tl * 132 + cl] = f2bf(outv);
      }
    }
  __syncthreads();

  #pragma unroll
  for (int it = 0; it < 8; ++it) {
    const int id = wv * 8 + it;
    const int hl = id >> 4, q4 = (id >> 2) & 3, fi = id & 3;
    const int tile = (tg0 >> 5) + q4;
    if (type < 2) {
      const ushort* srow = Ot + (q4 * 32 + l31) * 132 + hl * 64 + fi * 16 + hi * 8;
      union { s16x4 h[2]; s16x8 v; } u;
      u.h[0] = *(const s16x4*)srow;
      u.h[1] = *(const s16x4*)(srow + 4);
      ushort* dst;
      if (type == 0) {
        const int h = (n0 >> 6) + hl;
        dst = Qp + (((size_t)(bq * 32 + h) * 64 + tile) * 4 + fi) * 512 + ln * 8;
      } else {
        const int h = ((n0 - 2048) >> 6) + hl;
        dst = Kp + (((size_t)(bq * 8 + h) * 64 + tile) * 4 + fi) * 512 + ln * 8;
      }
      *(s16x8*)dst = u.v;
    } else {
      const int hk = ((n0 - 2560) >> 6) + hl;
      const int col = hl * 64 + (fi & 1) * 32 + l31;
      const int row0 = q4 * 32 + (fi >> 1) * 16 + hi * 8;
      ushort o[8];
      #pragma unroll
      for (int j = 0; j < 8; ++j) o[j] = Ot[(row0 + j) * 132 + col];
      ushort* dst = Vp + (((size_t)(bq * 8 + hk) * 64 + tile) * 4 + fi) * 512 + ln * 8;
      *(s16x8*)dst = *(const s16x8*)o;
    }
  }
}

// ---------------- Wo GEMM: 128x128 tile, single-barrier engine, f32 store (r11) ----------------
__global__ __launch_bounds__(256) void gemm_bt_3b(const ushort* __restrict__ A,
                                                  const ushort* __restrict__ BT,
                                                  float* __restrict__ C, int M, int N, int K) {
  __shared__ __attribute__((aligned(128))) ushort smem[40960];   // 80 KiB
  ushort* Asm = smem;
  ushort* Bsm = smem + 16384;

  const int tid = threadIdx.x;
  const int ln = tid & 63, wv = tid >> 6;
  const int g = ln >> 4, l15 = ln & 15;
  const int wm = wv >> 1, wn = wv & 1;
  const int m0 = blockIdx.y * 128, n0 = blockIdx.x * 128;
  const int NKT = K / 64;

  f32x4 acc[4][4];
  #pragma unroll
  for (int i = 0; i < 4; ++i)
    #pragma unroll
    for (int j = 0; j < 4; ++j) acc[i][j] = (f32x4){0.f, 0.f, 0.f, 0.f};

  kloop3(A, BT, Asm, Bsm, m0, n0, K, NKT, acc, tid, wm, wn, g, l15);

  #pragma unroll
  for (int mi = 0; mi < 4; ++mi)
    #pragma unroll
    for (int r = 0; r < 4; ++r) {
      int row = m0 + wm * 64 + mi * 16 + g * 4 + r;
      float* crow = C + (size_t)row * N + n0 + wn * 64 + l15;
      #pragma unroll
      for (int ni = 0; ni < 4; ++ni) crow[ni * 16] = acc[mi][ni][r];
    }
}

// ---------------- causal GQA flash attention ----------------
// Round 19: DUAL-HEAD ILP.  The attn invariant (79-82 us across r15/r16/r18:
// VALU cut -> no change; occupancy raise -> no change) says the per-iteration
// dependency chain is the wall, and each wave carries exactly ONE chain.
// GQA: 4 q-heads share each kv-head.  Pair heads (hq0, hq0+1) for the same
// (b,hk,qtile) in ONE wave: identical K/V loads (shared, halves fetch) and
// masks, but TWO independent QK->softmax->PV chains that interleave on the
// SIMD, each hiding the other's latency.  2048 waves (single full pass),
// ~200 VGPR -> 2 waves/SIMD class; waves_per_eu(2,2) on a non-template
// kernel (r4-validated).  Separate LDS patch per head (no WAR hazard).
__global__ __attribute__((amdgpu_flat_work_group_size(64, 64)))
__attribute__((amdgpu_waves_per_eu(2, 2)))
void attn_k(const ushort* __restrict__ Qp,
            const ushort* __restrict__ Kp,
            const ushort* __restrict__ Vp,
            ushort* __restrict__ O) {
  __shared__ ushort ep[2][32 * 64];   // per-head epilogue transpose patch
  const int ln = threadIdx.x & 63;
  const int l31 = ln & 31, hi = ln >> 5;

  const int f = blockIdx.x;                  // 0..2047, one wave per block
  const int xcd = f & 7, j = f >> 3;         // j: 0..255
  const int pr = xcd + 8 * (j & 1);          // (b,hk) pair id, 0..15
  const int b = pr >> 3, hk = pr & 7;
  const int s = j >> 1;                      // 0..127
  const int hp = s & 1;                      // head pair: {0,1} or {2,3}
  const int hq0 = hk * 4 + hp * 2, hq1 = hq0 + 1;
  const int qtile = 63 - (s >> 1);           // LJF
  const int qw = qtile * 32;
  const int nt = qtile + 1;

  const ushort* QhA   = Qp + ((size_t)(b * 32 + hq0)) * (64 * 2048);
  const ushort* QhB   = Qp + ((size_t)(b * 32 + hq1)) * (64 * 2048);
  const ushort* Kbase = Kp + ((size_t)(b * 8 + hk)) * (64 * 2048);
  const ushort* Vbase = Vp + ((size_t)(b * 8 + hk)) * (64 * 2048);

  s16x8 qfA[4], qfB[4];
  {
    const ushort* qa = QhA + (size_t)qtile * 2048 + ln * 8;
    const ushort* qb = QhB + (size_t)qtile * 2048 + ln * 8;
    #pragma unroll
    for (int ks = 0; ks < 4; ++ks) {
      qfA[ks] = *(const s16x8*)(qa + ks * 512);
      qfB[ks] = *(const s16x8*)(qb + ks * 512);
    }
  }

  f32x16 z16;
  #pragma unroll
  for (int r = 0; r < 16; ++r) z16[r] = 0.f;

  f32x16 oaccA[2], oaccB[2];
  #pragma unroll
  for (int r = 0; r < 16; ++r) {
    oaccA[0][r] = 0.f; oaccA[1][r] = 0.f;
    oaccB[0][r] = 0.f; oaccB[1][r] = 0.f;
  }
  float mA = -1e30f, lA = 0.f, mB = -1e30f, lB = 0.f;

  const ushort* kp = Kbase + ln * 8;
  const ushort* vp = Vbase + ln * 8;

  s16x8 kf[4];
  #pragma unroll
  for (int ks = 0; ks < 4; ++ks) kf[ks] = *(const s16x8*)(kp + ks * 512);
  kp += 2048;

  s16x8 vc[4];
  union pfu { unsigned u[4]; s16x8 v; };
  pfu pfA0, pfA1, pfB0, pfB1;

  #pragma unroll 1
  for (int kt = 0; kt < nt; ++kt) {
    if (kt) {
      __builtin_amdgcn_s_setprio(1);
      oaccA[0] = MFMA32(vc[0], pfA0.v, oaccA[0], 0, 0, 0);
      oaccB[0] = MFMA32(vc[0], pfB0.v, oaccB[0], 0, 0, 0);
      oaccA[1] = MFMA32(vc[1], pfA0.v, oaccA[1], 0, 0, 0);
      oaccB[1] = MFMA32(vc[1], pfB0.v, oaccB[1], 0, 0, 0);
      oaccA[0] = MFMA32(vc[2], pfA1.v, oaccA[0], 0, 0, 0);
      oaccB[0] = MFMA32(vc[2], pfB1.v, oaccB[0], 0, 0, 0);
      oaccA[1] = MFMA32(vc[3], pfA1.v, oaccA[1], 0, 0, 0);
      oaccB[1] = MFMA32(vc[3], pfB1.v, oaccB[1], 0, 0, 0);
      __builtin_amdgcn_s_setprio(0);
    }
    #pragma unroll
    for (int fi2 = 0; fi2 < 4; ++fi2) vc[fi2] = *(const s16x8*)(vp + fi2 * 512);
    vp += 2048;

    __builtin_amdgcn_s_setprio(1);
    f32x16 spA = MFMA32(kf[0], qfA[0], z16, 0, 0, 0);
    f32x16 spB = MFMA32(kf[0], qfB[0], z16, 0, 0, 0);
    spA = MFMA32(kf[1], qfA[1], spA, 0, 0, 0);
    spB = MFMA32(kf[1], qfB[1], spB, 0, 0, 0);
    spA = MFMA32(kf[2], qfA[2], spA, 0, 0, 0);
    spB = MFMA32(kf[2], qfB[2], spB, 0, 0, 0);
    spA = MFMA32(kf[3], qfA[3], spA, 0, 0, 0);
    spB = MFMA32(kf[3], qfB[3], spB, 0, 0, 0);
    __builtin_amdgcn_s_setprio(0);

    if (kt + 1 < nt) {
      #pragma unroll
      for (int ks = 0; ks < 4; ++ks) kf[ks] = *(const s16x8*)(kp + ks * 512);
      kp += 2048;
    }

    if (kt == qtile) {
      #pragma unroll
      for (int r = 0; r < 16; ++r) {
        int key = (r & 3) + 8 * (r >> 2) + 4 * hi;
        if (key > l31) { spA[r] = -1e30f; spB[r] = -1e30f; }
      }
    }

    // row maxes (two independent trees; compiler interleaves)
    float pa, pb;
    {
      float t0 = fmaxf(fmaxf(spA[0], spA[1]), spA[2]);
      float t1 = fmaxf(fmaxf(spA[3], spA[4]), spA[5]);
      float t2 = fmaxf(fmaxf(spA[6], spA[7]), spA[8]);
      float t3 = fmaxf(fmaxf(spA[9], spA[10]), spA[11]);
      float t4 = fmaxf(fmaxf(spA[12], spA[13]), spA[14]);
      pa = plswap_max(fmaxf(fmaxf(fmaxf(t0, t1), t2), fmaxf(fmaxf(t3, t4), spA[15])));
      float u0 = fmaxf(fmaxf(spB[0], spB[1]), spB[2]);
      float u1 = fmaxf(fmaxf(spB[3], spB[4]), spB[5]);
      float u2 = fmaxf(fmaxf(spB[6], spB[7]), spB[8]);
      float u3 = fmaxf(fmaxf(spB[9], spB[10]), spB[11]);
      float u4 = fmaxf(fmaxf(spB[12], spB[13]), spB[14]);
      pb = plswap_max(fmaxf(fmaxf(fmaxf(u0, u1), u2), fmaxf(fmaxf(u3, u4), spB[15])));
    }

    // T13 defer-max per head
    if (__any(pa - mA > 8.0f)) {
      float mn = fmaxf(mA, pa);
      float alpha = __builtin_amdgcn_exp2f(mA - mn);
      mA = mn; lA *= alpha;
      #pragma unroll
      for (int r = 0; r < 16; ++r) { oaccA[0][r] *= alpha; oaccA[1][r] *= alpha; }
    }
    if (__any(pb - mB > 8.0f)) {
      float mn = fmaxf(mB, pb);
      float alpha = __builtin_amdgcn_exp2f(mB - mn);
      mB = mn; lB *= alpha;
      #pragma unroll
      for (int r = 0; r < 16; ++r) { oaccB[0][r] *= alpha; oaccB[1][r] *= alpha; }
    }

    #pragma unroll
    for (int r = 0; r < 16; ++r) {
      spA[r] = __builtin_amdgcn_exp2f(spA[r] - mA);
      spB[r] = __builtin_amdgcn_exp2f(spB[r] - mB);
    }
    {
      float a0 = spA[0] + spA[1], a1 = spA[2] + spA[3], a2 = spA[4] + spA[5], a3 = spA[6] + spA[7];
      float a4 = spA[8] + spA[9], a5 = spA[10] + spA[11], a6 = spA[12] + spA[13], a7 = spA[14] + spA[15];
      lA += plswap_sum(((a0 + a1) + (a2 + a3)) + ((a4 + a5) + (a6 + a7)));
      float b0 = spB[0] + spB[1], b1 = spB[2] + spB[3], b2 = spB[4] + spB[5], b3 = spB[6] + spB[7];
      float b4 = spB[8] + spB[9], b5 = spB[10] + spB[11], b6 = spB[12] + spB[13], b7 = spB[14] + spB[15];
      lB += plswap_sum(((b0 + b1) + (b2 + b3)) + ((b4 + b5) + (b6 + b7)));
    }

    unsigned cwA[8], cwB[8];
    #pragma unroll
    for (int jj = 0; jj < 8; ++jj) {
      union { __hip_bfloat162 h; unsigned u; } pk;
      pk.h = __float22bfloat162_rn(make_float2(spA[2 * jj], spA[2 * jj + 1]));
      cwA[jj] = pk.u;
      pk.h = __float22bfloat162_rn(make_float2(spB[2 * jj], spB[2 * jj + 1]));
      cwB[jj] = pk.u;
    }
    {
      u32x2 r;
      r = __builtin_amdgcn_permlane32_swap(cwA[0], cwA[2], false, false);
      pfA0.u[0] = r[0]; pfA0.u[2] = r[1];
      r = __builtin_amdgcn_permlane32_swap(cwA[1], cwA[3], false, false);
      pfA0.u[1] = r[0]; pfA0.u[3] = r[1];
      r = __builtin_amdgcn_permlane32_swap(cwA[4], cwA[6], false, false);
      pfA1.u[0] = r[0]; pfA1.u[2] = r[1];
      r = __builtin_amdgcn_permlane32_swap(cwA[5], cwA[7], false, false);
      pfA1.u[1] = r[0]; pfA1.u[3] = r[1];
      r = __builtin_amdgcn_permlane32_swap(cwB[0], cwB[2], false, false);
      pfB0.u[0] = r[0]; pfB0.u[2] = r[1];
      r = __builtin_amdgcn_permlane32_swap(cwB[1], cwB[3], false, false);
      pfB0.u[1] = r[0]; pfB0.u[3] = r[1];
      r = __builtin_amdgcn_permlane32_swap(cwB[4], cwB[6], false, false);
      pfB1.u[0] = r[0]; pfB1.u[2] = r[1];
      r = __builtin_amdgcn_permlane32_swap(cwB[5], cwB[7], false, false);
      pfB1.u[1] = r[0]; pfB1.u[3] = r[1];
    }
  }

  __builtin_amdgcn_s_setprio(1);
  oaccA[0] = MFMA32(vc[0], pfA0.v, oaccA[0], 0, 0, 0);
  oaccB[0] = MFMA32(vc[0], pfB0.v, oaccB[0], 0, 0, 0);
  oaccA[1] = MFMA32(vc[1], pfA0.v, oaccA[1], 0, 0, 0);
  oaccB[1] = MFMA32(vc[1], pfB0.v, oaccB[1], 0, 0, 0);
  oaccA[0] = MFMA32(vc[2], pfA1.v, oaccA[0], 0, 0, 0);
  oaccB[0] = MFMA32(vc[2], pfB1.v, oaccB[0], 0, 0, 0);
  oaccA[1] = MFMA32(vc[3], pfA1.v, oaccA[1], 0, 0, 0);
  oaccB[1] = MFMA32(vc[3], pfB1.v, oaccB[1], 0, 0, 0);
  __builtin_amdgcn_s_setprio(0);

  // ---- epilogue per head (separate LDS patches, single-wave, no barrier) ----
  const int qr = ln >> 1, half = ln & 1;
  {
    float invl = 1.0f / lA;
    ushort* lds = ep[0];
    #pragma unroll
    for (int dt = 0; dt < 2; ++dt)
      #pragma unroll
      for (int r = 0; r < 16; ++r) {
        int d = dt * 32 + (r & 3) + 8 * (r >> 2) + 4 * hi;
        int byte = (l31 * 128 + d * 2) ^ ((l31 & 7) << 4);
        *(ushort*)((char*)lds + byte) = f2bf(oaccA[dt][r] * invl);
      }
    #pragma unroll
    for (int jj = 0; jj < 4; ++jj) {
      int byte = (qr * 128 + half * 64 + jj * 16) ^ ((qr & 7) << 4);
      s16x8 vrow = *(const s16x8*)((const char*)lds + byte);
      *(s16x8*)(O + ((size_t)(b * 2048 + qw + qr)) * 2048 + hq0 * 64 + half * 32 + jj * 8) = vrow;
    }
  }
  {
    float invl = 1.0f / lB;
    ushort* lds = ep[1];
    #pragma unroll
    for (int dt = 0; dt < 2; ++dt)
      #pragma unroll
      for (int r = 0; r < 16; ++r) {
        int d = dt * 32 + (r & 3) + 8 * (r >> 2) + 4 * hi;
        int byte = (l31 * 128 + d * 2) ^ ((l31 & 7) << 4);
        *(ushort*)((char*)lds + byte) = f2bf(oaccB[dt][r] * invl);
      }
    #pragma unroll
    for (int jj = 0; jj < 4; ++jj) {
      int byte = (qr * 128 + half * 64 + jj * 16) ^ ((qr & 7) << 4);
      s16x8 vrow = *(const s16x8*)((const char*)lds + byte);
      *(s16x8*)(O + ((size_t)(b * 2048 + qw + qr)) * 2048 + hq1 * 64 + half * 32 + jj * 8) = vrow;
    }
  }
}

extern "C" void kernel_launch(void* const* d_in, const int* in_sizes, int n_in,
                              void* d_out, int out_size, void* d_ws, size_t ws_size,
                              hipStream_t stream) {
  const float* x   = (const float*)d_in[0];
  const float* Wq  = (const float*)d_in[1];
  const float* Wkv = (const float*)d_in[2];
  const float* Wo  = (const float*)d_in[3];
  float* out = (float*)d_out;

  char* ws = (char*)d_ws;
  ushort* xb     = (ushort*)(ws);                 // 16 MiB  x bf16 (4096x2048)
  ushort* WqkvT  = (ushort*)(ws + 16777216);      // 12 MiB  [Wq|Wkv]^T bf16 (3072x2048)
  ushort* WoT    = (ushort*)(ws + 29360128);      //  8 MiB  Wo^T bf16 (2048x2048)
  float2* tab    = (float2*)(ws + 37748736);      // 512 KiB rope tables
  ushort* Qp     = (ushort*)(ws + 38273024);      // 16 MiB  Q packed
  ushort* Kp     = (ushort*)(ws + 55050240);      //  4 MiB  K packed
  ushort* Vp     = (ushort*)(ws + 59244544);      //  4 MiB  V packed
  ushort* Ob     = (ushort*)(ws + 63438848);      // 16 MiB  attn out bf16 (4096x2048)

  preamble_k<<<11008, 256, 0, stream>>>(x, Wq, Wkv, Wo, xb, WqkvT, WoT, tab);
  gemm_qkv_3b<<<dim3(24, 32), 256, 0, stream>>>(xb, WqkvT, tab, Qp, Kp, Vp);
  attn_k<<<2048, 64, 0, stream>>>(Qp, Kp, Vp, Ob);
  gemm_bt_3b<<<dim3(16, 32), 256, 0, stream>>>(Ob, WoT, out, 4096, 2048, 2048);
}